// Round 1
// baseline (1169.569 us; speedup 1.0000x reference)
//
#include <hip/hip_runtime.h>
#include <hip/hip_bf16.h>
#include <math.h>

#define N_D   4096
#define N_M   8192
#define NN    12288
#define EDG   196608
#define HID   512
#define NPAIR 65536

typedef __attribute__((ext_vector_type(8))) short short8;
typedef __attribute__((ext_vector_type(4))) float f32x4;

__device__ __forceinline__ unsigned short f32_to_bf16(float f) {
  unsigned int u = __float_as_uint(f);
  u += 0x7fffu + ((u >> 16) & 1u);
  return (unsigned short)(u >> 16);
}

// ---------------- transpose + cast: src [K][Nn] fp32 -> dst [Nn][K] bf16 ----
__global__ __launch_bounds__(256) void transpose_cast_k(
    const float* __restrict__ src, unsigned short* __restrict__ dst,
    int K, int Nn)
{
  __shared__ unsigned short t[64][65];
  const int bk = blockIdx.x * 64;
  const int bn = blockIdx.y * 64;
  const int tid = threadIdx.x;
  #pragma unroll
  for (int j = 0; j < 16; ++j) {
    int i = tid + 256 * j;
    int r = i >> 6, c = i & 63;
    t[r][c] = f32_to_bf16(src[(size_t)(bk + r) * Nn + bn + c]);
  }
  __syncthreads();
  #pragma unroll
  for (int j = 0; j < 16; ++j) {
    int i = tid + 256 * j;
    int r = i >> 6, c = i & 63;
    dst[(size_t)(bn + r) * K + bk + c] = t[c][r];
  }
}

// ---------------- graph preprocessing ----------------
__global__ __launch_bounds__(256) void deg_count_k(const int* __restrict__ dst,
                                                   int* __restrict__ deg)
{
  int e = blockIdx.x * 256 + threadIdx.x;
  atomicAdd(&deg[dst[e]], 1);
}

__global__ __launch_bounds__(256) void norm_k(const int* __restrict__ deg,
                                              float* __restrict__ nrm)
{
  int n = blockIdx.x * 256 + threadIdx.x;
  int d = deg[n];
  nrm[n] = 1.0f / sqrtf((float)(d < 1 ? 1 : d));
}

// exclusive scan of deg[0:12288] -> rp[0:12289], single block of 1024
__global__ __launch_bounds__(1024) void scan_k(const int* __restrict__ deg,
                                               int* __restrict__ rp)
{
  __shared__ int sums[1024];
  const int t = threadIdx.x;
  int local[12];
  int s = 0;
  #pragma unroll
  for (int i = 0; i < 12; ++i) { local[i] = deg[t * 12 + i]; s += local[i]; }
  sums[t] = s;
  __syncthreads();
  for (int off = 1; off < 1024; off <<= 1) {
    int v = (t >= off) ? sums[t - off] : 0;
    __syncthreads();
    sums[t] += v;
    __syncthreads();
  }
  int run = (t == 0) ? 0 : sums[t - 1];
  #pragma unroll
  for (int i = 0; i < 12; ++i) { rp[t * 12 + i] = run; run += local[i]; }
  if (t == 1023) rp[12288] = run;
}

__global__ __launch_bounds__(256) void csr_fill_k(
    const int* __restrict__ src, const int* __restrict__ dst,
    const float* __restrict__ nrm, const int* __restrict__ rp,
    int* __restrict__ cur, int* __restrict__ col, float* __restrict__ wgt)
{
  int e = blockIdx.x * 256 + threadIdx.x;
  int d = dst[e];
  int p = rp[d] + atomicAdd(&cur[d], 1);
  int s = src[e];
  col[p] = s;
  wgt[p] = nrm[s] * nrm[d];
}

// ---------------- bf16 MFMA GEMM: C[M,512] = A[M,K](fp32) * Bt[512,K](bf16)^T
#define BM 128
#define BN 128
#define BK 64
#define LDSP 72  // 64 + 8 bf16 pad -> 2-way bank aliasing only (free)

__global__ __launch_bounds__(256) void gemm_f32a_bf16bt(
    const float* __restrict__ A, const unsigned short* __restrict__ Bt,
    float* __restrict__ C, int M, int K)
{
  __shared__ unsigned short lA[BM * LDSP];
  __shared__ unsigned short lB[BN * LDSP];
  const int tid = threadIdx.x;
  const int lane = tid & 63;
  const int wave = tid >> 6;
  const int wm = (wave >> 1) * 64;
  const int wn = (wave & 1) * 64;
  const int m0 = blockIdx.y * BM;
  const int n0 = blockIdx.x * BN;
  f32x4 acc[4][4];
  const f32x4 zero = {0.f, 0.f, 0.f, 0.f};
  #pragma unroll
  for (int i = 0; i < 4; ++i)
    #pragma unroll
    for (int j = 0; j < 4; ++j) acc[i][j] = zero;

  const int kTiles = K / BK;
  for (int kt = 0; kt < kTiles; ++kt) {
    const int k0 = kt * BK;
    __syncthreads();
    // stage A tile 128x64 fp32 -> bf16 LDS
    #pragma unroll
    for (int j = 0; j < 8; ++j) {
      int i = tid + 256 * j;
      int r = i >> 4;
      int c = (i & 15) * 4;
      const float4 v = *reinterpret_cast<const float4*>(&A[(size_t)(m0 + r) * K + k0 + c]);
      unsigned long long pk =
            (unsigned long long)f32_to_bf16(v.x)
          | ((unsigned long long)f32_to_bf16(v.y) << 16)
          | ((unsigned long long)f32_to_bf16(v.z) << 32)
          | ((unsigned long long)f32_to_bf16(v.w) << 48);
      *reinterpret_cast<unsigned long long*>(&lA[r * LDSP + c]) = pk;
    }
    // stage Bt tile 128x64 bf16 (already [n][k] packed)
    #pragma unroll
    for (int j = 0; j < 4; ++j) {
      int i = tid + 256 * j;
      int r = i >> 3;
      int c = (i & 7) * 8;
      const int4 v = *reinterpret_cast<const int4*>(&Bt[(size_t)(n0 + r) * K + k0 + c]);
      *reinterpret_cast<int4*>(&lB[r * LDSP + c]) = v;
    }
    __syncthreads();
    #pragma unroll
    for (int ks = 0; ks < 2; ++ks) {
      const int kk = ks * 32 + (lane >> 4) * 8;
      short8 af[4], bfr[4];
      #pragma unroll
      for (int mi = 0; mi < 4; ++mi)
        af[mi] = *reinterpret_cast<const short8*>(&lA[(wm + mi * 16 + (lane & 15)) * LDSP + kk]);
      #pragma unroll
      for (int ni = 0; ni < 4; ++ni)
        bfr[ni] = *reinterpret_cast<const short8*>(&lB[(wn + ni * 16 + (lane & 15)) * LDSP + kk]);
      #pragma unroll
      for (int mi = 0; mi < 4; ++mi)
        #pragma unroll
        for (int ni = 0; ni < 4; ++ni)
          acc[mi][ni] = __builtin_amdgcn_mfma_f32_16x16x32_bf16(af[mi], bfr[ni], acc[mi][ni], 0, 0, 0);
    }
  }
  // epilogue: C/D layout col=lane&15, row=(lane>>4)*4+reg (m89-verified)
  #pragma unroll
  for (int mi = 0; mi < 4; ++mi) {
    #pragma unroll
    for (int ni = 0; ni < 4; ++ni) {
      const int colI = n0 + wn + ni * 16 + (lane & 15);
      const int rbase = m0 + wm + mi * 16 + (lane >> 4) * 4;
      #pragma unroll
      for (int r = 0; r < 4; ++r)
        C[(size_t)(rbase + r) * 512 + colI] = acc[mi][ni][r];
    }
  }
}

// ---------------- SpMM: Tout[n,:] = Yk[n,:] + sum_e w_e * Tin[col_e,:] ------
__global__ __launch_bounds__(128) void spmm_k(
    const int* __restrict__ rp, const int* __restrict__ col,
    const float* __restrict__ wgt, const float* __restrict__ Tin,
    const float* __restrict__ Yk, const float* __restrict__ bias,
    float* __restrict__ Tout, int addBias)
{
  const int n = blockIdx.x;
  const int c0 = threadIdx.x * 4;
  float4 acc = *reinterpret_cast<const float4*>(&Yk[(size_t)n * HID + c0]);
  const int e1 = rp[n + 1];
  int e = rp[n];
  for (; e + 1 < e1; e += 2) {
    int s0 = col[e], s1 = col[e + 1];
    float w0 = wgt[e], w1 = wgt[e + 1];
    float4 v0 = *reinterpret_cast<const float4*>(&Tin[(size_t)s0 * HID + c0]);
    float4 v1 = *reinterpret_cast<const float4*>(&Tin[(size_t)s1 * HID + c0]);
    acc.x += w0 * v0.x + w1 * v1.x;
    acc.y += w0 * v0.y + w1 * v1.y;
    acc.z += w0 * v0.z + w1 * v1.z;
    acc.w += w0 * v0.w + w1 * v1.w;
  }
  if (e < e1) {
    int s0 = col[e];
    float w0 = wgt[e];
    float4 v0 = *reinterpret_cast<const float4*>(&Tin[(size_t)s0 * HID + c0]);
    acc.x += w0 * v0.x; acc.y += w0 * v0.y; acc.z += w0 * v0.z; acc.w += w0 * v0.w;
  }
  if (addBias) {
    float4 b4 = *reinterpret_cast<const float4*>(&bias[c0]);
    acc.x += b4.x; acc.y += b4.y; acc.z += b4.z; acc.w += b4.w;
  }
  *reinterpret_cast<float4*>(&Tout[(size_t)n * HID + c0]) = acc;
}

// ---------------- per-node predictor precompute ----------------
__global__ __launch_bounds__(128) void node_ab_g_k(
    const float* __restrict__ h, const float* __restrict__ Wp,
    float* __restrict__ a, float* __restrict__ b, float* __restrict__ g)
{
  const int n = blockIdx.x;
  const int tid = threadIdx.x;
  const int c0 = tid * 4;
  float4 hv = *reinterpret_cast<const float4*>(&h[(size_t)n * HID + c0]);
  float4 w1 = *reinterpret_cast<const float4*>(&Wp[c0]);
  float4 w2 = *reinterpret_cast<const float4*>(&Wp[HID + c0]);
  float4 w3 = *reinterpret_cast<const float4*>(&Wp[2 * HID + c0]);
  float pa = hv.x * w1.x + hv.y * w1.y + hv.z * w1.z + hv.w * w1.w;
  float pb = hv.x * w2.x + hv.y * w2.y + hv.z * w2.z + hv.w * w2.w;
  if (n < N_D) {
    float4 gv;
    gv.x = hv.x * w3.x; gv.y = hv.y * w3.y; gv.z = hv.z * w3.z; gv.w = hv.w * w3.w;
    *reinterpret_cast<float4*>(&g[(size_t)n * HID + c0]) = gv;
  }
  #pragma unroll
  for (int off = 32; off > 0; off >>= 1) {
    pa += __shfl_down(pa, off);
    pb += __shfl_down(pb, off);
  }
  __shared__ float sA[2], sB[2];
  const int lane = tid & 63, wv = tid >> 6;
  if (lane == 0) { sA[wv] = pa; sB[wv] = pb; }
  __syncthreads();
  if (tid == 0) { a[n] = sA[0] + sA[1]; b[n] = sB[0] + sB[1]; }
}

// ---------------- pair scoring: wave per pair ----------------
__global__ __launch_bounds__(256) void pairs_kernel(
    const int* __restrict__ dis, const int* __restrict__ mir,
    const float* __restrict__ h, const float* __restrict__ g,
    const float* __restrict__ a, const float* __restrict__ b,
    const float* __restrict__ bp, float* __restrict__ out)
{
  const int gw = (int)((blockIdx.x * 256 + threadIdx.x) >> 6);
  const int lane = threadIdx.x & 63;
  if (gw >= NPAIR) return;
  const int d = dis[gw];
  const int m = mir[gw];
  const float4* gr = reinterpret_cast<const float4*>(&g[(size_t)d * HID + lane * 8]);
  const float4* hr = reinterpret_cast<const float4*>(&h[(size_t)m * HID + lane * 8]);
  float4 g0 = gr[0], g1 = gr[1];
  float4 h0 = hr[0], h1 = hr[1];
  float s = g0.x * h0.x + g0.y * h0.y + g0.z * h0.z + g0.w * h0.w
          + g1.x * h1.x + g1.y * h1.y + g1.z * h1.z + g1.w * h1.w;
  #pragma unroll
  for (int off = 32; off > 0; off >>= 1) s += __shfl_down(s, off);
  if (lane == 0) {
    float logit = s + a[d] + b[m] + bp[0];
    out[gw] = 1.0f / (1.0f + expf(-logit));
  }
}

// ---------------- launcher ----------------
extern "C" void kernel_launch(void* const* d_in, const int* in_sizes, int n_in,
                              void* d_out, int out_size, void* d_ws, size_t ws_size,
                              hipStream_t stream)
{
  const float* d_sim = (const float*)d_in[0];
  const float* m_sim = (const float*)d_in[1];
  const int*   src   = (const int*)d_in[2];
  const int*   dst   = (const int*)d_in[3];
  const int*   dis   = (const int*)d_in[4];
  const int*   mir   = (const int*)d_in[5];
  const float* Wd    = (const float*)d_in[6];
  const float* Wm    = (const float*)d_in[7];
  const float* Wf    = (const float*)d_in[8];
  const float* bf    = (const float*)d_in[9];
  const float* Wp    = (const float*)d_in[10];
  const float* bp    = (const float*)d_in[11];
  float* out = (float*)d_out;
  char* ws = (char*)d_ws;

  const size_t SZ_NODE = (size_t)NN * HID * 4;  // 25165824 B
  float* X  = (float*)(ws);
  float* Yb = (float*)(ws + SZ_NODE);
  float* T0 = (float*)(ws + 2 * SZ_NODE);
  float* T1 = (float*)(ws + 3 * SZ_NODE);
  unsigned short* WdT = (unsigned short*)(ws + 4 * SZ_NODE);
  unsigned short* WmT = (unsigned short*)((char*)WdT + (size_t)512 * 4096 * 2);
  unsigned short* WfT = (unsigned short*)((char*)WmT + (size_t)512 * 8192 * 2);
  float* G   = (float*)((char*)WfT + (size_t)2560 * 512 * 2);
  int*   deg = (int*)((char*)G + (size_t)N_D * HID * 4);
  float* nrm = (float*)((char*)deg + 49152);
  int*   rp  = (int*)((char*)nrm + 49152);
  int*   cur = (int*)((char*)rp + 49408);
  int*   col = (int*)((char*)cur + 49152);
  float* wgt = (float*)((char*)col + (size_t)EDG * 4);
  float* av  = (float*)((char*)wgt + (size_t)EDG * 4);
  float* bv  = (float*)((char*)av + 49152);

  // ---- pack weights to bf16, transposed [N][K] ----
  transpose_cast_k<<<dim3(64, 8), 256, 0, stream>>>(Wd, WdT, 4096, 512);
  transpose_cast_k<<<dim3(128, 8), 256, 0, stream>>>(Wm, WmT, 8192, 512);
  for (int k = 0; k < 5; ++k)
    transpose_cast_k<<<dim3(8, 8), 256, 0, stream>>>(
        Wf + (size_t)k * 512 * 512, WfT + (size_t)k * 512 * 512, 512, 512);

  // ---- graph: degrees, norms, CSR by dst ----
  hipMemsetAsync(deg, 0, 49152, stream);
  hipMemsetAsync(cur, 0, 49152, stream);
  deg_count_k<<<EDG / 256, 256, 0, stream>>>(dst, deg);
  norm_k<<<NN / 256, 256, 0, stream>>>(deg, nrm);
  scan_k<<<1, 1024, 0, stream>>>(deg, rp);
  csr_fill_k<<<EDG / 256, 256, 0, stream>>>(src, dst, nrm, rp, cur, col, wgt);

  // ---- X = [d_sim@Wd ; m_sim@Wm] ----
  gemm_f32a_bf16bt<<<dim3(4, 32), 256, 0, stream>>>(d_sim, WdT, X, 4096, 4096);
  gemm_f32a_bf16bt<<<dim3(4, 64), 256, 0, stream>>>(m_sim, WmT, X + (size_t)N_D * HID, 8192, 8192);

  // ---- Horner: h = Y0 + A(Y1 + A(Y2 + A(Y3 + A*Y4))) + bf ----
  gemm_f32a_bf16bt<<<dim3(4, 96), 256, 0, stream>>>(X, WfT + (size_t)4 * 512 * 512, T0, NN, 512);
  float* tin = T0;
  float* tout = T1;
  for (int k = 3; k >= 0; --k) {
    gemm_f32a_bf16bt<<<dim3(4, 96), 256, 0, stream>>>(X, WfT + (size_t)k * 512 * 512, Yb, NN, 512);
    spmm_k<<<NN, 128, 0, stream>>>(rp, col, wgt, tin, Yb, bf, tout, (k == 0) ? 1 : 0);
    float* tmp = tin; tin = tout; tout = tmp;
  }
  float* h = tin;  // == T0

  // ---- predictor ----
  node_ab_g_k<<<NN, 128, 0, stream>>>(h, Wp, av, bv, G);
  pairs_kernel<<<NPAIR / 4, 256, 0, stream>>>(dis, mir, h, G, av, bv, bp, out);
}